// Round 1
// baseline (209.240 us; speedup 1.0000x reference)
//
#include <hip/hip_runtime.h>
#include <hip/hip_bf16.h>
#include <stdint.h>

// Problem constants (reference: B=2, D=128, H=64, W=64)
#define BN 2
#define DN 128
#define MN 4096                 // H*W pixels per image
#define TOTAL_INV (1.0f / 33554432.0f)   // 1 / (B*M*N)

typedef __attribute__((ext_vector_type(8))) short short8;   // 8 bf16 = 4 VGPRs
typedef __attribute__((ext_vector_type(4))) float f32x4;

__device__ static inline unsigned short f2bf(float x) {
  // round-to-nearest-even f32 -> bf16 (inputs are finite normals)
  unsigned int u = __float_as_uint(x);
  u += 0x7fffu + ((u >> 16) & 1u);
  return (unsigned short)(u >> 16);
}

__device__ static inline void async16(const void* g, void* l) {
  // 16B global -> LDS direct copy (dest = wave-uniform base + lane*16)
  __builtin_amdgcn_global_load_lds(
      (const __attribute__((address_space(1))) void*)g,
      (__attribute__((address_space(3))) void*)l, 16, 0, 0);
}

// [B, D, M] f32  ->  [B, M, D] bf16(ushort), 64x64 LDS tile transpose
__global__ __launch_bounds__(256) void transpose_cvt(
    const float* __restrict__ s0, const float* __restrict__ s1,
    unsigned short* __restrict__ o0, unsigned short* __restrict__ o1) {
  __shared__ float tile[64][65];          // +1 pad: conflict-free transpose
  const int tx = threadIdx.x & 63;
  const int ty = threadIdx.x >> 6;        // 0..3 (wave id)
  const int m0 = blockIdx.x * 64;
  const int d0 = blockIdx.y * 64;
  const int b  = blockIdx.z & 1;
  const float* src = (blockIdx.z >> 1) ? s1 : s0;
  unsigned short* dst = (blockIdx.z >> 1) ? o1 : o0;
  src += (size_t)b * DN * MN;
  dst += (size_t)b * MN * DN;
#pragma unroll
  for (int i = 0; i < 16; ++i) {
    int dr = i * 4 + ty;
    tile[dr][tx] = src[(size_t)(d0 + dr) * MN + m0 + tx];  // 256B coalesced / wave
  }
  __syncthreads();
#pragma unroll
  for (int i = 0; i < 16; ++i) {
    int mr = i * 4 + ty;
    dst[(size_t)(m0 + mr) * DN + d0 + tx] = f2bf(tile[tx][mr]);  // 128B coalesced
  }
}

// Fused bf16 MFMA GEMM (C = A * B^T, both [M,K] row-major) + hinge loss + mean.
// grid: (N/128, M/128, B), block: 256 (4 waves, 2x2; each wave 64x64 = 4x4 MFMAs)
__global__ __launch_bounds__(256) void gemm_loss(
    const unsigned short* __restrict__ A, const unsigned short* __restrict__ Bm,
    const void* __restrict__ maskp, float* __restrict__ out) {
  __shared__ __align__(16) unsigned short As[128 * 32];  // 8 KB, [m][k] k-contig
  __shared__ __align__(16) unsigned short Bs[128 * 32];  // 8 KB, [n][k] k-contig
  __shared__ float red[4];
  __shared__ int mask_is_u8;

  const int tid  = threadIdx.x;
  const int lane = tid & 63;
  const int wave = tid >> 6;
  const int wm = wave >> 1, wn = wave & 1;
  const int quad = lane >> 4;
  const int l16  = lane & 15;
  const int bn = blockIdx.x, bm = blockIdx.y, bz = blockIdx.z;

  // ---- mask dtype sniff: int32 {0,1} has zero bytes at offset%4!=0 ----
  if (tid == 0) mask_is_u8 = 0;
  __syncthreads();
  if (((const unsigned int*)maskp)[tid] & 0xFFFFFF00u) mask_is_u8 = 1;  // benign race
  // (barrier before use happens inside the K-loop)

  const unsigned short* Ab = A  + (size_t)bz * MN * DN + (size_t)(bm * 128) * DN;
  const unsigned short* Bb = Bm + (size_t)bz * MN * DN + (size_t)(bn * 128) * DN;

  f32x4 acc[4][4];
#pragma unroll
  for (int i = 0; i < 4; ++i)
#pragma unroll
    for (int j = 0; j < 4; ++j) acc[i][j] = (f32x4){0.f, 0.f, 0.f, 0.f};

#pragma unroll
  for (int kt = 0; kt < 4; ++kt) {
    const int k0 = kt * 32;
    // stage 128x32 bf16 tiles: 512 x 16B chunks, 2 per thread, lane-contiguous LDS
#pragma unroll
    for (int p = 0; p < 2; ++p) {
      int c = tid + p * 256;
      int row = c >> 2;      // 4 chunks (64B) per row
      int cq  = c & 3;
      async16(Ab + (size_t)row * DN + k0 + cq * 8, As + c * 8);
      async16(Bb + (size_t)row * DN + k0 + cq * 8, Bs + c * 8);
    }
    __syncthreads();  // compiler emits vmcnt(0) drain here

    short8 af[4], bf[4];
#pragma unroll
    for (int mi = 0; mi < 4; ++mi)   // ds_read_b128: A[m=l16][k=quad*8..+8]
      af[mi] = *(const short8*)(As + (wm * 64 + mi * 16 + l16) * 32 + quad * 8);
#pragma unroll
    for (int ni = 0; ni < 4; ++ni)
      bf[ni] = *(const short8*)(Bs + (wn * 64 + ni * 16 + l16) * 32 + quad * 8);
#pragma unroll
    for (int mi = 0; mi < 4; ++mi)
#pragma unroll
      for (int ni = 0; ni < 4; ++ni)
        acc[mi][ni] = __builtin_amdgcn_mfma_f32_16x16x32_bf16(
            af[mi], bf[ni], acc[mi][ni], 0, 0, 0);
    __syncthreads();
  }

  // ---- epilogue: hinge loss under mask, block reduction, one atomic ----
  // C/D layout: col = lane&15 (n), row = quad*4 + r (m)
  const size_t mbase =
      ((size_t)bz * MN + (size_t)(bm * 128 + wm * 64)) * MN + (size_t)(bn * 128 + wn * 64);
  const int* mi32 = (const int*)maskp;
  const unsigned char* mu8 = (const unsigned char*)maskp;
  const int u8 = mask_is_u8;
  float lsum = 0.0f;
#pragma unroll
  for (int mi = 0; mi < 4; ++mi) {
#pragma unroll
    for (int ni = 0; ni < 4; ++ni) {
      f32x4 v = acc[mi][ni];
#pragma unroll
      for (int r = 0; r < 4; ++r) {
        int m = mi * 16 + quad * 4 + r;
        int n = ni * 16 + l16;
        size_t idx = mbase + (size_t)m * MN + n;
        int msk = u8 ? (int)mu8[idx] : mi32[idx];
        float dot = v[r];
        float pos = fmaxf(0.0f, 1.0f - dot) * 250.0f;
        float neg = fmaxf(0.0f, dot - 0.2f);
        lsum += msk ? pos : neg;
      }
    }
  }
#pragma unroll
  for (int off = 32; off > 0; off >>= 1) lsum += __shfl_xor(lsum, off);
  if (lane == 0) red[wave] = lsum;
  __syncthreads();
  if (tid == 0) {
    float t = (red[0] + red[1] + red[2] + red[3]) * TOTAL_INV;
    atomicAdd(out, t);   // device-scope float atomic; d_out zeroed by memset
  }
}

extern "C" void kernel_launch(void* const* d_in, const int* in_sizes, int n_in,
                              void* d_out, int out_size, void* d_ws, size_t ws_size,
                              hipStream_t stream) {
  const float* d0 = (const float*)d_in[0];
  const float* d1 = (const float*)d_in[1];
  const void* mask = d_in[2];
  float* out = (float*)d_out;

  unsigned short* Aw = (unsigned short*)d_ws;            // [B, M, D] bf16, 2 MB
  unsigned short* Bw = Aw + (size_t)BN * MN * DN;        // [B, M, D] bf16, 2 MB

  // d_out is re-poisoned to 0xAA before every replay -> must zero it here
  hipMemsetAsync(d_out, 0, sizeof(float), stream);

  dim3 g1(MN / 64, DN / 64, BN * 2), b1(256);
  transpose_cvt<<<g1, b1, 0, stream>>>(d0, d1, Aw, Bw);

  dim3 g2(MN / 128, MN / 128, BN), b2(256);
  gemm_loss<<<g2, b2, 0, stream>>>(Aw, Bw, mask, out);
}